// Round 4
// baseline (738.824 us; speedup 1.0000x reference)
//
#include <hip/hip_runtime.h>
#include <cstdint>

// Problem: B=32, N=4096, C=768, H=12, hd=64, L=32, chunk=24
// Identity: out[b,l,c'] = (sum_n attn[b,l,n] x[b,n,:]) . v_w[l*24+c',:] + v_b
// Pipeline:
//   k0:  qbf = bf16(latent * 0.125); zero sums
//   K1:  REGISTER-DIRECT, barrier-free: per (b, 64-n tile, 4-head third),
//        each lane's 16 float4 loads ARE its MFMA B-frags (perfect tiling);
//        same regs -> coalesced xbf store; E=exp(S) bf16; sums via atomics.
//   KW:  per (b,l): rs[h] = 1/(12*sums); W[b,l,n] = sum_h E*rs (1 E pass)
//   K3:  4-wave LDS-staged GEMM, software-pipelined (prefetch t+1, compute t)
//   K4:  out = (sum_g y) . v_w^T + v_b

typedef short bf16x8 __attribute__((ext_vector_type(8)));
typedef float f32x4 __attribute__((ext_vector_type(4)));

#define MFMA16(a, b, c) __builtin_amdgcn_mfma_f32_16x16x32_bf16((a), (b), (c), 0, 0, 0)

// pack two f32 -> (bf16(a) | bf16(b)<<16) by byte-select (truncation, 1 VALU)
__device__ __forceinline__ uint32_t pk_bf16(float a, float b) {
    return __builtin_amdgcn_perm(__float_as_uint(b), __float_as_uint(a), 0x07060302u);
}
__device__ __forceinline__ unsigned short bf16_trunc(float f) {
    return (unsigned short)(__float_as_uint(f) >> 16);
}
__device__ __forceinline__ float bf16_lo(uint32_t u) { return __uint_as_float(u << 16); }
__device__ __forceinline__ float bf16_hi(uint32_t u) { return __uint_as_float(u & 0xffff0000u); }

// ---------------------------------------------------------------------------
// k0: qbf[h][l][d] = bf16(latent[l][h*64+d] * 0.125) (24576 elems); zero sums.
// ---------------------------------------------------------------------------
__global__ __launch_bounds__(256)
void k0_init(const float* __restrict__ latent, unsigned short* __restrict__ qbf,
             float* __restrict__ sums)
{
    int i = blockIdx.x * 256 + threadIdx.x;       // 0..24575
    if (i < 12288) sums[i] = 0.f;
    int l = i / 768;
    int r = i - l * 768;
    int h = r >> 6, d = r & 63;
    qbf[(h * 32 + l) * 64 + d] = bf16_trunc(latent[i] * 0.125f);
}

// ---------------------------------------------------------------------------
// K1: block = (b, 64-n tile, head-third hb). NO x LDS, NO mid-kernel barriers.
// Perfect frag tiling: lane (wv,quad,lc) owns row n = nn0+wv*16+lc and
// d-chunks quad*8..+8 of each (head, ks): 16 float4 loads cover the 64nx256c
// slice exactly once and land directly in MFMA B-fragment layout.
// Same packed regs -> xbf store (4x16B/thread/head-pair, 64B/row segments).
// MFMA 16x16x32: A[m=lane&15][k=quad*8+j] from qbf (L1-hot), D col=lane&15,
// row=quad*4+reg. E=exp(S) truncated bf16; quad shfl-reduce -> block sums ->
// one atomicAdd per (h,l). grid = 32*3*64 = 6144 blocks x 256.
// ---------------------------------------------------------------------------
__global__ __launch_bounds__(256)
void k1_logits(const float* __restrict__ x, const unsigned short* __restrict__ qbf,
               unsigned short* __restrict__ E, unsigned short* __restrict__ xbf,
               float* __restrict__ sums)
{
    const int bx    = blockIdx.x;       // ((b*3 + hb)*64 + ntile)
    const int ntile = bx & 63;
    const int bh    = bx >> 6;          // 0..95
    const int hb    = bh % 3;           // head-third: heads hb*4..hb*4+3
    const int bb    = bh / 3;           // batch
    const int nn0   = ntile << 6;

    const int tid  = threadIdx.x;
    const int wv   = tid >> 6;
    const int lane = tid & 63;
    const int quad = lane >> 4;
    const int lc   = lane & 15;

    __shared__ float bsum[4][32][4];    // 2 KB only

    const int n = nn0 + wv * 16 + lc;   // this lane's n-row (and E column)
    const float* xr = x + (size_t)(bb * 4096 + n) * 768 + hb * 256 + quad * 8;
    unsigned short* xbr = xbf + (size_t)(bb * 4096 + n) * 768 + hb * 256 + quad * 8;

    #pragma unroll
    for (int hp = 0; hp < 2; ++hp) {    // head pairs: heads hb*4+hp*2 .. +1
        // ---- 8 independent 16B loads: (h2, ks, half) -> d = h*64+ks*32+quad*8+half*4
        float4 v[8];
        #pragma unroll
        for (int j = 0; j < 8; ++j) {
            const int h2 = j >> 2, ks = (j >> 1) & 1, hf = j & 1;
            v[j] = *(const float4*)&xr[(hp * 2 + h2) * 64 + ks * 32 + hf * 4];
        }
        // ---- pack to bf16 (truncation, same math as before)
        uint2 pk[8];
        #pragma unroll
        for (int j = 0; j < 8; ++j) {
            pk[j].x = pk_bf16(v[j].x, v[j].y);
            pk[j].y = pk_bf16(v[j].z, v[j].w);
        }
        // ---- xbf stores: per (h2,ks) one 16B store; 4 quads/row -> 64B segments
        #pragma unroll
        for (int j = 0; j < 4; ++j) {   // j = h2*2 + ks
            const int h2 = j >> 1, ks = j & 1;
            uint4 st;
            st.x = pk[j * 2].x; st.y = pk[j * 2].y;
            st.z = pk[j * 2 + 1].x; st.w = pk[j * 2 + 1].y;
            *(uint4*)&xbr[(hp * 2 + h2) * 64 + ks * 32] = st;
        }
        // ---- per head: MFMA + exp + E store + quad reduce
        #pragma unroll
        for (int h2 = 0; h2 < 2; ++h2) {
            const int hg = hb * 4 + hp * 2 + h2;
            const unsigned short* qh = qbf + hg * 2048;
            bf16x8 a00 = *(const bf16x8*)&qh[lc * 64 + quad * 8];
            bf16x8 a01 = *(const bf16x8*)&qh[lc * 64 + 32 + quad * 8];
            bf16x8 a10 = *(const bf16x8*)&qh[(16 + lc) * 64 + quad * 8];
            bf16x8 a11 = *(const bf16x8*)&qh[(16 + lc) * 64 + 32 + quad * 8];
            union { uint2 u[2]; bf16x8 v8; } b0u, b1u;
            b0u.u[0] = pk[h2 * 4 + 0]; b0u.u[1] = pk[h2 * 4 + 1];  // ks=0: d 0..31
            b1u.u[0] = pk[h2 * 4 + 2]; b1u.u[1] = pk[h2 * 4 + 3];  // ks=1: d 32..63

            f32x4 c0 = {0.f, 0.f, 0.f, 0.f};
            f32x4 c1 = {0.f, 0.f, 0.f, 0.f};
            c0 = MFMA16(a00, b0u.v8, c0);
            c0 = MFMA16(a01, b1u.v8, c0);
            c1 = MFMA16(a10, b0u.v8, c1);
            c1 = MFMA16(a11, b1u.v8, c1);

            // E = exp(S) truncated; sum the TRUNCATED value so KW's
            // denominators match the stored numerators exactly.
            unsigned short* Eh = E + (size_t)((bb * 12 + hg) * 32) * 4096;
            float sv[8];
            #pragma unroll
            for (int r = 0; r < 4; ++r) {
                // |S| <~ 0.2: exp without max-subtraction is exact softmax math
                uint32_t u0 = __float_as_uint(__expf(c0[r]));
                uint32_t u1 = __float_as_uint(__expf(c1[r]));
                Eh[(quad * 4 + r) * 4096 + n]      = (unsigned short)(u0 >> 16);
                Eh[(16 + quad * 4 + r) * 4096 + n] = (unsigned short)(u1 >> 16);
                sv[r]     = __uint_as_float(u0 & 0xffff0000u);
                sv[4 + r] = __uint_as_float(u1 & 0xffff0000u);
            }
            // reduce over the 16 n-cols of this quad (masks 1,2,4,8 in-quad)
            #pragma unroll
            for (int m = 1; m < 16; m <<= 1) {
                #pragma unroll
                for (int k = 0; k < 8; ++k) sv[k] += __shfl_xor(sv[k], m);
            }
            if (lc == 0) {
                #pragma unroll
                for (int r = 0; r < 4; ++r) {
                    bsum[hp * 2 + h2][quad * 4 + r][wv]      = sv[r];
                    bsum[hp * 2 + h2][16 + quad * 4 + r][wv] = sv[4 + r];
                }
            }
        }
    }

    __syncthreads();
    if (tid < 128) {
        const int h = tid >> 5, l = tid & 31;
        atomicAdd(&sums[(bb * 12 + hb * 4 + h) * 32 + l],
                  bsum[h][l][0] + bsum[h][l][1] + bsum[h][l][2] + bsum[h][l][3]);
    }
}

// ---------------------------------------------------------------------------
// KW: block = (b,l), 256 thr. rs[h] from precomputed sums (K1 atomics);
// single E pass: W[b,l,n] = sum_h E * 1/(12*sums[h]). No atomics here.
// ---------------------------------------------------------------------------
__global__ __launch_bounds__(256)
void kw_weights(const unsigned short* __restrict__ E, const float* __restrict__ sums,
                unsigned short* __restrict__ W)
{
    const int b = blockIdx.x >> 5;
    const int l = blockIdx.x & 31;
    const int tid = threadIdx.x;

    const unsigned short* Eb = E + (size_t)(b * 384 + l) * 4096;  // +h*32*4096
    __shared__ float rsl[12];
    if (tid < 12) rsl[tid] = 1.0f / (12.0f * sums[(b * 12 + tid) * 32 + l]);
    __syncthreads();

    float acc[16];
    #pragma unroll
    for (int i = 0; i < 16; ++i) acc[i] = 0.f;
    #pragma unroll
    for (int h = 0; h < 12; ++h) {
        float r = rsl[h];
        const uint4* p = (const uint4*)(Eb + (size_t)h * 131072 + tid * 16);
        uint4 u0 = p[0], u1 = p[1];
        acc[0] += bf16_lo(u0.x) * r;  acc[1] += bf16_hi(u0.x) * r;
        acc[2] += bf16_lo(u0.y) * r;  acc[3] += bf16_hi(u0.y) * r;
        acc[4] += bf16_lo(u0.z) * r;  acc[5] += bf16_hi(u0.z) * r;
        acc[6] += bf16_lo(u0.w) * r;  acc[7] += bf16_hi(u0.w) * r;
        acc[8] += bf16_lo(u1.x) * r;  acc[9] += bf16_hi(u1.x) * r;
        acc[10] += bf16_lo(u1.y) * r; acc[11] += bf16_hi(u1.y) * r;
        acc[12] += bf16_lo(u1.z) * r; acc[13] += bf16_hi(u1.z) * r;
        acc[14] += bf16_lo(u1.w) * r; acc[15] += bf16_hi(u1.w) * r;
    }
    uint4 o0, o1;
    o0.x = pk_bf16(acc[0], acc[1]);   o0.y = pk_bf16(acc[2], acc[3]);
    o0.z = pk_bf16(acc[4], acc[5]);   o0.w = pk_bf16(acc[6], acc[7]);
    o1.x = pk_bf16(acc[8], acc[9]);   o1.y = pk_bf16(acc[10], acc[11]);
    o1.z = pk_bf16(acc[12], acc[13]); o1.w = pk_bf16(acc[14], acc[15]);
    uint4* wp = (uint4*)(W + (size_t)(b * 32 + l) * 4096 + tid * 16);
    wp[0] = o0; wp[1] = o1;
}

// ---------------------------------------------------------------------------
// K3: LDS-staged GEMM, software-pipelined. block = (b, cn, kg):
// y[kg][b][l][c0..c0+128] = sum_{n in kg*512..+512} W[b][l][n] * xbf[b][n][c].
// Per BK=64 iter: prefetch t+1 to regs, COMPUTE t (hides HBM latency), then
// sync/write/sync. xl pad 130: u16 column-gathers conflict-free (banks
// 8*quad + lc/2 (+65j) cover all 32; even/odd lc share a dword -> broadcast).
// grid = 32*6*8 = 1536 blocks x 256 (4 waves; wave owns 32 c). ~7 blocks/CU.
// ---------------------------------------------------------------------------
__global__ __launch_bounds__(256)
void yacc_kernel(const unsigned short* __restrict__ xbf, const unsigned short* __restrict__ W,
                 float* __restrict__ yws)
{
    const int bx = blockIdx.x;          // ((b*6 + cn)*8 + kg)
    const int kg = bx & 7;
    const int bc = bx >> 3;
    const int cn = bc % 6;
    const int b  = bc / 6;
    const int c0 = cn * 128;
    const int n00 = kg * 512;

    const int tid  = threadIdx.x;
    const int wv   = tid >> 6;
    const int lane = tid & 63;
    const int quad = lane >> 4;
    const int lc   = lane & 15;

    __shared__ __align__(16) unsigned short wl[32][72];    // 4.6 KB
    __shared__ __align__(16) unsigned short xl[64][130];   // 16.6 KB

    const unsigned short* Wb = W + (size_t)b * 32 * 4096;
    const unsigned short* xb = xbf + (size_t)b * 4096 * 768;

    f32x4 acc[2][2];
    #pragma unroll
    for (int t = 0; t < 2; ++t)
        #pragma unroll
        for (int cs = 0; cs < 2; ++cs) acc[t][cs] = (f32x4){0.f, 0.f, 0.f, 0.f};

    const int wrow = tid >> 3, wchk = tid & 7;   // W stage: 8 lanes/row

    uint4 wreg;
    uint4 xreg[4];

    // ---- prologue: load + stage iter 0 ----
    wreg = *(const uint4*)&Wb[(size_t)wrow * 4096 + n00 + wchk * 8];
    #pragma unroll
    for (int k = 0; k < 4; ++k) {
        const int m = tid + k * 256;
        xreg[k] = *(const uint4*)&xb[(size_t)(n00 + (m >> 4)) * 768 + c0 + (m & 15) * 8];
    }
    *(uint4*)&wl[wrow][wchk * 8] = wreg;
    #pragma unroll
    for (int k = 0; k < 4; ++k) {
        const int m = tid + k * 256;
        *(uint4*)&xl[m >> 4][(m & 15) * 8] = xreg[k];
    }
    __syncthreads();

    for (int it = 0; it < 8; ++it) {
        // ---- prefetch iter t+1 into regs (latency hides under compute) ----
        if (it < 7) {
            const int n0 = n00 + (it + 1) * 64;
            wreg = *(const uint4*)&Wb[(size_t)wrow * 4096 + n0 + wchk * 8];
            #pragma unroll
            for (int k = 0; k < 4; ++k) {
                const int m = tid + k * 256;
                xreg[k] = *(const uint4*)&xb[(size_t)(n0 + (m >> 4)) * 768 + c0 + (m & 15) * 8];
            }
        }
        // ---- compute iter t: 2 k-steps x (2 A-frags, 2 B-frags) = 8 MFMA ----
        #pragma unroll
        for (int ks = 0; ks < 2; ++ks) {
            bf16x8 a0 = *(const bf16x8*)&wl[lc][ks * 32 + quad * 8];
            bf16x8 a1 = *(const bf16x8*)&wl[16 + lc][ks * 32 + quad * 8];
            #pragma unroll
            for (int cs = 0; cs < 2; ++cs) {
                const int cc = wv * 32 + cs * 16 + lc;
                const unsigned short* col = &xl[ks * 32 + quad * 8][cc];
                uint32_t e0 = col[0],       e1 = col[130];
                uint32_t e2 = col[2 * 130], e3 = col[3 * 130];
                uint32_t e4 = col[4 * 130], e5 = col[5 * 130];
                uint32_t e6 = col[6 * 130], e7 = col[7 * 130];
                union { uint32_t u[4]; bf16x8 v; } bbu;
                bbu.u[0] = e0 | (e1 << 16);
                bbu.u[1] = e2 | (e3 << 16);
                bbu.u[2] = e4 | (e5 << 16);
                bbu.u[3] = e6 | (e7 << 16);
                acc[0][cs] = MFMA16(a0, bbu.v, acc[0][cs]);
                acc[1][cs] = MFMA16(a1, bbu.v, acc[1][cs]);
            }
        }
        // ---- stage iter t+1 ----
        if (it < 7) {
            __syncthreads();   // everyone done reading xl/wl
            *(uint4*)&wl[wrow][wchk * 8] = wreg;
            #pragma unroll
            for (int k = 0; k < 4; ++k) {
                const int m = tid + k * 256;
                *(uint4*)&xl[m >> 4][(m & 15) * 8] = xreg[k];
            }
            __syncthreads();
        }
    }

    // D col=lane&15 -> c = c0 + wv*32 + cs*16 + lc; row=quad*4+r -> l
    float* yp = yws + (size_t)((kg * 32 + b) * 32) * 768;
    #pragma unroll
    for (int t = 0; t < 2; ++t)
        #pragma unroll
        for (int cs = 0; cs < 2; ++cs)
            #pragma unroll
            for (int r = 0; r < 4; ++r)
                yp[(t * 16 + quad * 4 + r) * 768 + c0 + wv * 32 + cs * 16 + lc] = acc[t][cs][r];
}

// ---------------------------------------------------------------------------
// K4: out[b, l*24+i] = sum_c (sum_g y[g,b,l,c]) * v_w[l*24+i, c] + v_b
// ---------------------------------------------------------------------------
__global__ __launch_bounds__(256)
void out_kernel(const float* __restrict__ yws, const float* __restrict__ vw,
                const float* __restrict__ vb, float* __restrict__ out)
{
    const int b = blockIdx.x >> 5;
    const int l = blockIdx.x & 31;
    const int tid = threadIdx.x;
    __shared__ float y_lds[768];
    for (int c = tid; c < 768; c += 256) {
        float v = 0.f;
        #pragma unroll
        for (int g = 0; g < 8; ++g)
            v += yws[(size_t)((g * 32 + b) * 32 + l) * 768 + c];
        y_lds[c] = v;
    }
    __syncthreads();
    const int wv = tid >> 6, lane = tid & 63;
    for (int i = wv; i < 24; i += 4) {
        const int row = l * 24 + i;
        const float* wr = vw + row * 768;
        float p = 0.f;
        #pragma unroll
        for (int j = 0; j < 12; ++j)
            p += y_lds[j * 64 + lane] * wr[j * 64 + lane];
        #pragma unroll
        for (int m = 1; m < 64; m <<= 1) p += __shfl_xor(p, m);
        if (lane == 0) out[b * 768 + row] = p + vb[row];
    }
}

// ---------------------------------------------------------------------------
extern "C" void kernel_launch(void* const* d_in, const int* in_sizes, int n_in,
                              void* d_out, int out_size, void* d_ws, size_t ws_size,
                              hipStream_t stream)
{
    const float* x      = (const float*)d_in[0];  // [32,4096,768]
    const float* latent = (const float*)d_in[1];  // [1,32,768]
    const float* vw     = (const float*)d_in[2];  // [768,768]
    const float* vb     = (const float*)d_in[3];  // [768]
    float* out = (float*)d_out;                   // [32,768]

    // ws layout (~336 MB; ws_size ~1.6 GB):
    //   [0, 100663296)              E    bf16[32][12][32][4096]
    //   [100663296, 109051904)      W    bf16[32][32][4096]
    //   [109051904, 134217728)      y    f32[8][32][32][768]
    //   [134217728, 335544320)      xbf  bf16[32][4096][768]  (natural layout)
    //   [335544320, +49152)         qbf  bf16[12][32][64]
    //   [335609856, +49152)         sums f32[32][12][32]
    char* ws = (char*)d_ws;
    unsigned short* E    = (unsigned short*)ws;
    unsigned short* W    = (unsigned short*)(ws + 100663296);
    float*          yws  = (float*)(ws + 109051904);
    unsigned short* xbf  = (unsigned short*)(ws + 134217728);
    unsigned short* qbf  = (unsigned short*)(ws + 335544320);
    float*          sums = (float*)(ws + 335609856);

    k0_init<<<dim3(96), dim3(256), 0, stream>>>(latent, qbf, sums);
    k1_logits<<<dim3(6144), dim3(256), 0, stream>>>(x, qbf, E, xbf, sums);
    kw_weights<<<dim3(1024), dim3(256), 0, stream>>>(E, sums, W);
    yacc_kernel<<<dim3(1536), dim3(256), 0, stream>>>(xbf, W, yws);
    out_kernel<<<dim3(1024), dim3(256), 0, stream>>>(yws, vw, vb, out);
}